// Round 1
// baseline (1205.378 us; speedup 1.0000x reference)
//
#include <hip/hip_runtime.h>
#include <hip/hip_bf16.h>

#define B_   8
#define C1_  256
#define C2_  256
#define Cm_  128    // C_ = C2/2
#define H_   80
#define W_   80
#define HW_  6400
#define CN_  1152   // C_ * 9
#define EPS_ 1e-5f

// ---------------- Kernel 1: h = SiLU(BN1(W1 @ x)) ----------------
// grid: (HW/64, B), block 256. LDS-staged x chunks, wave-uniform W1 reads.
__global__ __launch_bounds__(256) void k1_cv1(
    const float* __restrict__ x, const float* __restrict__ W1,
    const float* __restrict__ g1, const float* __restrict__ b1,
    const float* __restrict__ m1, const float* __restrict__ v1,
    float* __restrict__ h) {
  __shared__ float xs[64][64];   // [cc][px]
  const int b   = blockIdx.y;
  const int hw0 = blockIdx.x * 64;
  const int t   = threadIdx.x;
  const int px  = t & 63;
  const int og  = __builtin_amdgcn_readfirstlane(t >> 6);  // 0..3, wave-uniform

  float acc[32];
#pragma unroll
  for (int k = 0; k < 32; ++k) acc[k] = 0.f;

  for (int c0 = 0; c0 < C1_; c0 += 64) {
#pragma unroll
    for (int i = 0; i < 16; ++i) {
      int idx = t + i * 256;
      int cc = idx >> 6, pp = idx & 63;
      xs[cc][pp] = x[((size_t)b * C1_ + (c0 + cc)) * HW_ + hw0 + pp];
    }
    __syncthreads();
    for (int cc = 0; cc < 64; ++cc) {
      float xv = xs[cc][px];
      const float* wrow = &W1[(og * 32) * C1_ + c0 + cc];
#pragma unroll
      for (int k = 0; k < 32; ++k)
        acc[k] = fmaf(wrow[k * C1_], xv, acc[k]);
    }
    __syncthreads();
  }
#pragma unroll
  for (int k = 0; k < 32; ++k) {
    int o = og * 32 + k;
    float s   = g1[o] * rsqrtf(v1[o] + EPS_);
    float val = (acc[k] - m1[o]) * s + b1[o];
    float sig = 1.f / (1.f + __expf(-val));
    h[((size_t)b * Cm_ + o) * HW_ + hw0 + px] = val * sig;
  }
}

// ---------------- Kernel 2: fused RFA (weights + softmax + conv + epilogue) ---
// grid: (W/8, H, B), block 256.
__global__ __launch_bounds__(256) void k2_rfa(
    const float* __restrict__ h,  const float* __restrict__ x,
    const float* __restrict__ Wg, const float* __restrict__ bg,
    const float* __restrict__ gg, const float* __restrict__ bgw,
    const float* __restrict__ mg, const float* __restrict__ vg,
    const float* __restrict__ Wc, const float* __restrict__ bc,
    const float* __restrict__ g2, const float* __restrict__ b2,
    const float* __restrict__ m2, const float* __restrict__ v2,
    float* __restrict__ out) {
  __shared__ float ht[Cm_ * 30];     // [c][r(3)][xx(10)]
  __shared__ float vbuf[CN_][8];     // weighted patches, [c*9+n][px]

  const int b  = blockIdx.z;
  const int y  = blockIdx.y;
  const int x0 = blockIdx.x * 8;
  const int t  = threadIdx.x;

  // phase 0: stage h halo tile (rows y-1..y+1, cols x0-1..x0+8), zero-padded
  for (int idx = t; idx < Cm_ * 30; idx += 256) {
    int c   = idx / 30;
    int rem = idx - c * 30;
    int r   = rem / 10;
    int xx  = rem - r * 10;
    int gy  = y + r - 1;
    int gx  = x0 + xx - 1;
    float val = 0.f;
    if (gy >= 0 && gy < H_ && gx >= 0 && gx < W_)
      val = h[((size_t)b * Cm_ + c) * HW_ + gy * W_ + gx];
    ht[idx] = val;
  }
  __syncthreads();

  // phase 1: per (c, px): 9->9 mixing + BN + softmax -> weighted patches
#pragma unroll
  for (int k = 0; k < 4; ++k) {
    int id = t + k * 256;       // 0..1023
    int c  = id >> 3;           // 0..127
    int px = id & 7;            // 0..7
    float p[9];
#pragma unroll
    for (int i = 0; i < 3; ++i)
#pragma unroll
      for (int j = 0; j < 3; ++j)
        p[i * 3 + j] = ht[c * 30 + i * 10 + px + j];
    float wv[9];
#pragma unroll
    for (int o = 0; o < 9; ++o) {
      float acc = bg[c * 9 + o];
#pragma unroll
      for (int i = 0; i < 9; ++i)
        acc = fmaf(Wg[c * 81 + o * 9 + i], p[i], acc);
      float s = gg[c * 9 + o] * rsqrtf(vg[c * 9 + o] + EPS_);
      wv[o] = (acc - mg[c * 9 + o]) * s + bgw[c * 9 + o];
    }
    float mx = wv[0];
#pragma unroll
    for (int o = 1; o < 9; ++o) mx = fmaxf(mx, wv[o]);
    float sum = 0.f;
#pragma unroll
    for (int o = 0; o < 9; ++o) { wv[o] = __expf(wv[o] - mx); sum += wv[o]; }
    float inv = 1.f / sum;
#pragma unroll
    for (int n = 0; n < 9; ++n)
      vbuf[c * 9 + n][px] = p[n] * wv[n] * inv;
  }
  __syncthreads();

  // phase 2: out[o, px] = sum_cn Wc[o][cn] * vbuf[cn][px]
  const int o = t;              // 0..255
  float acc[8];
#pragma unroll
  for (int i = 0; i < 8; ++i) acc[i] = 0.f;
  const float* wcp = &Wc[(size_t)o * CN_];
  for (int cn4 = 0; cn4 < CN_; cn4 += 4) {
    const float4 wc4 = *reinterpret_cast<const float4*>(wcp + cn4);
#pragma unroll
    for (int u = 0; u < 4; ++u) {
      float wc = (u == 0) ? wc4.x : (u == 1) ? wc4.y : (u == 2) ? wc4.z : wc4.w;
      int cn = cn4 + u;
      const float4 va = *reinterpret_cast<const float4*>(&vbuf[cn][0]);
      const float4 vb = *reinterpret_cast<const float4*>(&vbuf[cn][4]);
      acc[0] = fmaf(wc, va.x, acc[0]);
      acc[1] = fmaf(wc, va.y, acc[1]);
      acc[2] = fmaf(wc, va.z, acc[2]);
      acc[3] = fmaf(wc, va.w, acc[3]);
      acc[4] = fmaf(wc, vb.x, acc[4]);
      acc[5] = fmaf(wc, vb.y, acc[5]);
      acc[6] = fmaf(wc, vb.z, acc[6]);
      acc[7] = fmaf(wc, vb.w, acc[7]);
    }
  }
  // epilogue: +bc, BN2, ReLU, +x residual
  float s    = g2[o] * rsqrtf(v2[o] + EPS_);
  float bias = bc[o];
#pragma unroll
  for (int px = 0; px < 8; ++px) {
    float val = (acc[px] + bias - m2[o]) * s + b2[o];
    val = fmaxf(val, 0.f);
    size_t oidx = ((size_t)b * C2_ + o) * HW_ + y * W_ + x0 + px;
    out[oidx] = x[oidx] + val;
  }
}

extern "C" void kernel_launch(void* const* d_in, const int* in_sizes, int n_in,
                              void* d_out, int out_size, void* d_ws, size_t ws_size,
                              hipStream_t stream) {
  (void)in_sizes; (void)n_in; (void)out_size; (void)ws_size;
  const float* x   = (const float*)d_in[0];
  const float* W1  = (const float*)d_in[1];
  const float* g1  = (const float*)d_in[2];
  const float* b1  = (const float*)d_in[3];
  const float* m1  = (const float*)d_in[4];
  const float* v1  = (const float*)d_in[5];
  const float* Wg  = (const float*)d_in[6];
  const float* bg  = (const float*)d_in[7];
  const float* gg  = (const float*)d_in[8];
  const float* bgw = (const float*)d_in[9];
  const float* mg  = (const float*)d_in[10];
  const float* vg  = (const float*)d_in[11];
  const float* Wc  = (const float*)d_in[12];
  const float* bc  = (const float*)d_in[13];
  const float* g2  = (const float*)d_in[14];
  const float* b2  = (const float*)d_in[15];
  const float* m2  = (const float*)d_in[16];
  const float* v2  = (const float*)d_in[17];
  float* outp = (float*)d_out;
  float* h    = (float*)d_ws;   // 8*128*6400 floats = 26.2 MB

  dim3 grid1(HW_ / 64, B_);
  k1_cv1<<<grid1, 256, 0, stream>>>(x, W1, g1, b1, m1, v1, h);

  dim3 grid2(W_ / 8, H_, B_);
  k2_rfa<<<grid2, 256, 0, stream>>>(h, x, Wg, bg, gg, bgw, mg, vg,
                                    Wc, bc, g2, b2, m2, v2, outp);
}

// Round 2
// 460.184 us; speedup vs baseline: 2.6193x; 2.6193x over previous
//
#include <hip/hip_runtime.h>
#include <hip/hip_bf16.h>

#define B_   8
#define C1_  256
#define C2_  256
#define Cm_  128    // C_ = C2/2
#define H_   80
#define W_   80
#define HW_  6400
#define CN_  1152   // C_ * 9
#define EPS_ 1e-5f

typedef __attribute__((ext_vector_type(8))) short bf16x8;
typedef __attribute__((ext_vector_type(4))) float f32x4;

__device__ inline unsigned short f2bf(float f) {
  union { float f; unsigned int u; } v; v.f = f;
  unsigned int u = v.u;
  unsigned int r = (u + 0x7FFFu + ((u >> 16) & 1u)) >> 16;
  return (unsigned short)r;
}
__device__ inline float bf2f(unsigned short s) {
  union { unsigned int u; float f; } v; v.u = ((unsigned int)s) << 16;
  return v.f;
}

// ---------------- Kernel 0: prep — Wc->bf16, BN2 scale/shift ----------------
__global__ __launch_bounds__(256) void k0_prep(
    const float* __restrict__ Wc, const float* __restrict__ bc,
    const float* __restrict__ g2, const float* __restrict__ b2,
    const float* __restrict__ m2, const float* __restrict__ v2,
    unsigned short* __restrict__ Wcb, float* __restrict__ A2,
    float* __restrict__ B2) {
  int idx = blockIdx.x * 256 + threadIdx.x;
  if (idx < C2_ * CN_) Wcb[idx] = f2bf(Wc[idx]);
  if (idx < C2_) {
    float s = g2[idx] * rsqrtf(v2[idx] + EPS_);
    A2[idx] = s;
    B2[idx] = (bc[idx] - m2[idx]) * s + b2[idx];
  }
}

// ---------------- Kernel 1: h = SiLU(BN1(W1 @ x)), bf16 out ----------------
__global__ __launch_bounds__(256) void k1_cv1(
    const float* __restrict__ x, const float* __restrict__ W1,
    const float* __restrict__ g1, const float* __restrict__ b1,
    const float* __restrict__ m1, const float* __restrict__ v1,
    unsigned short* __restrict__ h) {
  __shared__ float xs[64][64];   // [cc][px]
  const int b   = blockIdx.y;
  const int hw0 = blockIdx.x * 64;
  const int t   = threadIdx.x;
  const int px  = t & 63;
  const int og  = __builtin_amdgcn_readfirstlane(t >> 6);  // 0..3, wave-uniform

  float acc[32];
#pragma unroll
  for (int k = 0; k < 32; ++k) acc[k] = 0.f;

  for (int c0 = 0; c0 < C1_; c0 += 64) {
#pragma unroll
    for (int i = 0; i < 16; ++i) {
      int idx = t + i * 256;
      int cc = idx >> 6, pp = idx & 63;
      xs[cc][pp] = x[((size_t)b * C1_ + (c0 + cc)) * HW_ + hw0 + pp];
    }
    __syncthreads();
    for (int cc = 0; cc < 64; ++cc) {
      float xv = xs[cc][px];
      const float* wrow = &W1[(og * 32) * C1_ + c0 + cc];
#pragma unroll
      for (int k = 0; k < 32; ++k)
        acc[k] = fmaf(wrow[k * C1_], xv, acc[k]);
    }
    __syncthreads();
  }
#pragma unroll
  for (int k = 0; k < 32; ++k) {
    int o = og * 32 + k;
    float s   = g1[o] * rsqrtf(v1[o] + EPS_);
    float val = (acc[k] - m1[o]) * s + b1[o];
    float sig = 1.f / (1.f + __expf(-val));
    h[((size_t)b * Cm_ + o) * HW_ + hw0 + px] = f2bf(val * sig);
  }
}

// ---------------- Kernel 2a: softmax weights -> v_t[b][hw][cn] bf16 ---------
// grid: (W/8, H, B), block 256.
__global__ __launch_bounds__(256) void k2a_weights(
    const unsigned short* __restrict__ h,
    const float* __restrict__ Wg, const float* __restrict__ bg,
    const float* __restrict__ gg, const float* __restrict__ bgw,
    const float* __restrict__ mg, const float* __restrict__ vg,
    unsigned short* __restrict__ vt) {
  __shared__ unsigned short ht[Cm_ * 30];     // [c][r(3)][xx(10)] bf16
  __shared__ unsigned short vbuf[8][CN_];     // [px][c*9+n] bf16

  const int b  = blockIdx.z;
  const int y  = blockIdx.y;
  const int x0 = blockIdx.x * 8;
  const int t  = threadIdx.x;

  // phase 0: stage h halo tile (rows y-1..y+1, cols x0-1..x0+8), zero-padded
  for (int idx = t; idx < Cm_ * 30; idx += 256) {
    int c   = idx / 30;
    int rem = idx - c * 30;
    int r   = rem / 10;
    int xx  = rem - r * 10;
    int gy  = y + r - 1;
    int gx  = x0 + xx - 1;
    unsigned short val = 0;
    if (gy >= 0 && gy < H_ && gx >= 0 && gx < W_)
      val = h[((size_t)b * Cm_ + c) * HW_ + gy * W_ + gx];
    ht[idx] = val;
  }
  __syncthreads();

  // phase 1: per (c, px): 9->9 mixing + BN + softmax -> weighted patches
#pragma unroll
  for (int k = 0; k < 4; ++k) {
    int id = t + k * 256;       // 0..1023
    int c  = id >> 3;           // 0..127
    int px = id & 7;            // 0..7
    float p[9];
#pragma unroll
    for (int i = 0; i < 3; ++i)
#pragma unroll
      for (int j = 0; j < 3; ++j)
        p[i * 3 + j] = bf2f(ht[c * 30 + i * 10 + px + j]);
    float wv[9];
#pragma unroll
    for (int o = 0; o < 9; ++o) {
      float acc = bg[c * 9 + o];
#pragma unroll
      for (int i = 0; i < 9; ++i)
        acc = fmaf(Wg[c * 81 + o * 9 + i], p[i], acc);
      float s = gg[c * 9 + o] * rsqrtf(vg[c * 9 + o] + EPS_);
      wv[o] = (acc - mg[c * 9 + o]) * s + bgw[c * 9 + o];
    }
    float mx = wv[0];
#pragma unroll
    for (int o = 1; o < 9; ++o) mx = fmaxf(mx, wv[o]);
    float sum = 0.f;
#pragma unroll
    for (int o = 0; o < 9; ++o) { wv[o] = __expf(wv[o] - mx); sum += wv[o]; }
    float inv = 1.f / sum;
#pragma unroll
    for (int n = 0; n < 9; ++n)
      vbuf[px][c * 9 + n] = f2bf(p[n] * wv[n] * inv);
  }
  __syncthreads();

  // write-out: coalesced 16-B chunks, v_t[b][hw][cn]
  for (int idx = t; idx < 8 * (CN_ / 8); idx += 256) {   // 1152 chunks
    int px  = idx / 144;
    int off = idx - px * 144;
    const uint4* src = reinterpret_cast<const uint4*>(&vbuf[px][off * 8]);
    int hw = y * W_ + x0 + px;
    uint4* dst = reinterpret_cast<uint4*>(vt + ((size_t)b * HW_ + hw) * CN_ + off * 8);
    *dst = *src;
  }
}

// ---------------- Kernel 2b: out = x + relu(BN2(Wcb @ v_t + bc)) via MFMA ---
// grid: (HW/64, B), block 256 (4 waves). Wave w owns m-frags [4w..4w+3] x 4 n-frags.
__global__ __launch_bounds__(256) void k2b_gemm(
    const unsigned short* __restrict__ Wcb, const unsigned short* __restrict__ vt,
    const float* __restrict__ A2, const float* __restrict__ B2,
    const float* __restrict__ x, float* __restrict__ out) {
  const int b   = blockIdx.y;
  const int n0  = blockIdx.x * 64;
  const int t   = threadIdx.x;
  const int w   = __builtin_amdgcn_readfirstlane(t >> 6);
  const int l   = t & 63;
  const int l15 = l & 15;
  const int lhi = l >> 4;

  const unsigned short* aptr = Wcb + (size_t)(w * 64 + l15) * CN_ + 8 * lhi;
  const unsigned short* bptr = vt + ((size_t)b * HW_ + n0 + l15) * CN_ + 8 * lhi;

  f32x4 acc[4][4];
#pragma unroll
  for (int i = 0; i < 4; ++i)
#pragma unroll
    for (int nf = 0; nf < 4; ++nf) acc[i][nf] = (f32x4)0.f;

  bf16x8 a0[4], b0v[4], a1[4], b1v[4];

#define LOADA(DST, KK)                                                        \
  _Pragma("unroll") for (int i = 0; i < 4; ++i)                               \
      DST[i] = *reinterpret_cast<const bf16x8*>(aptr + i * 16 * CN_ + (KK));
#define LOADB(DST, KK)                                                        \
  _Pragma("unroll") for (int nf = 0; nf < 4; ++nf)                            \
      DST[nf] = *reinterpret_cast<const bf16x8*>(bptr + nf * 16 * CN_ + (KK));
#define MF(AS, BS)                                                            \
  _Pragma("unroll") for (int i = 0; i < 4; ++i)                               \
      _Pragma("unroll") for (int nf = 0; nf < 4; ++nf)                        \
          acc[i][nf] = __builtin_amdgcn_mfma_f32_16x16x32_bf16(               \
              AS[i], BS[nf], acc[i][nf], 0, 0, 0);

  LOADA(a0, 0) LOADB(b0v, 0)
  for (int kb = 0; kb < 17; ++kb) {
    const int kk = kb * 64;
    LOADA(a1, kk + 32) LOADB(b1v, kk + 32)
    MF(a0, b0v)
    LOADA(a0, kk + 64) LOADB(b0v, kk + 64)
    MF(a1, b1v)
  }
  LOADA(a1, 1120) LOADB(b1v, 1120)
  MF(a0, b0v)   // kk = 1088
  MF(a1, b1v)   // kk = 1120

  // epilogue: BN2 + ReLU + residual
#pragma unroll
  for (int i = 0; i < 4; ++i) {
#pragma unroll
    for (int r = 0; r < 4; ++r) {
      int o = w * 64 + i * 16 + lhi * 4 + r;
      float sA = A2[o], sB = B2[o];
#pragma unroll
      for (int nf = 0; nf < 4; ++nf) {
        float val = fmaf(acc[i][nf][r], sA, sB);
        val = fmaxf(val, 0.f);
        size_t idx = ((size_t)b * C2_ + o) * HW_ + n0 + nf * 16 + l15;
        out[idx] = x[idx] + val;
      }
    }
  }
#undef LOADA
#undef LOADB
#undef MF
}

extern "C" void kernel_launch(void* const* d_in, const int* in_sizes, int n_in,
                              void* d_out, int out_size, void* d_ws, size_t ws_size,
                              hipStream_t stream) {
  (void)in_sizes; (void)n_in; (void)out_size; (void)ws_size;
  const float* x   = (const float*)d_in[0];
  const float* W1  = (const float*)d_in[1];
  const float* g1  = (const float*)d_in[2];
  const float* b1  = (const float*)d_in[3];
  const float* m1  = (const float*)d_in[4];
  const float* v1  = (const float*)d_in[5];
  const float* Wg  = (const float*)d_in[6];
  const float* bg  = (const float*)d_in[7];
  const float* gg  = (const float*)d_in[8];
  const float* bgw = (const float*)d_in[9];
  const float* mg  = (const float*)d_in[10];
  const float* vg  = (const float*)d_in[11];
  const float* Wc  = (const float*)d_in[12];
  const float* bc  = (const float*)d_in[13];
  const float* g2  = (const float*)d_in[14];
  const float* b2  = (const float*)d_in[15];
  const float* m2  = (const float*)d_in[16];
  const float* v2  = (const float*)d_in[17];
  float* outp = (float*)d_out;

  // workspace layout (bytes):
  //   h   : bf16 [8][128][6400]      13,107,200
  //   v_t : bf16 [8][6400][1152]    117,964,800
  //   Wcb : bf16 [256][1152]            589,824
  //   A2,B2: f32 [256] each               2,048
  char* ws = (char*)d_ws;
  unsigned short* h   = (unsigned short*)ws;
  unsigned short* vt  = (unsigned short*)(ws + 13107200);
  unsigned short* Wcb = (unsigned short*)(ws + 13107200 + 117964800);
  float*          A2  = (float*)(ws + 13107200 + 117964800 + 589824);
  float*          B2  = A2 + C2_;

  k0_prep<<<dim3((C2_ * CN_ + 255) / 256), 256, 0, stream>>>(
      Wc, bc, g2, b2, m2, v2, Wcb, A2, B2);

  dim3 grid1(HW_ / 64, B_);
  k1_cv1<<<grid1, 256, 0, stream>>>(x, W1, g1, b1, m1, v1, h);

  dim3 grid2a(W_ / 8, H_, B_);
  k2a_weights<<<grid2a, 256, 0, stream>>>(h, Wg, bg, gg, bgw, mg, vg, vt);

  dim3 grid2b(HW_ / 64, B_);
  k2b_gemm<<<grid2b, 256, 0, stream>>>(Wcb, vt, A2, B2, x, outp);
}

// Round 4
// 314.057 us; speedup vs baseline: 3.8381x; 1.4653x over previous
//
#include <hip/hip_runtime.h>
#include <hip/hip_bf16.h>

#define B_   8
#define C1_  256
#define C2_  256
#define Cm_  128    // C_ = C2/2
#define H_   80
#define W_   80
#define HW_  6400
#define CN_  1152   // C_ * 9
#define EPS_ 1e-5f

typedef __attribute__((ext_vector_type(8))) short bf16x8;
typedef __attribute__((ext_vector_type(4))) float f32x4;

__device__ inline unsigned short f2bf(float f) {
  union { float f; unsigned int u; } v; v.f = f;
  unsigned int u = v.u;
  unsigned int r = (u + 0x7FFFu + ((u >> 16) & 1u)) >> 16;
  return (unsigned short)r;
}
__device__ inline float bf2f(unsigned short s) {
  union { unsigned int u; float f; } v; v.u = ((unsigned int)s) << 16;
  return v.f;
}

// ---------------- Kernel 0: prep — Wc->bf16, BN2 scale/shift ----------------
__global__ __launch_bounds__(256) void k0_prep(
    const float* __restrict__ Wc, const float* __restrict__ bc,
    const float* __restrict__ g2, const float* __restrict__ b2,
    const float* __restrict__ m2, const float* __restrict__ v2,
    unsigned short* __restrict__ Wcb, float* __restrict__ A2,
    float* __restrict__ B2) {
  int idx = blockIdx.x * 256 + threadIdx.x;
  if (idx < C2_ * CN_) Wcb[idx] = f2bf(Wc[idx]);
  if (idx < C2_) {
    float s = g2[idx] * rsqrtf(v2[idx] + EPS_);
    A2[idx] = s;
    B2[idx] = (bc[idx] - m2[idx]) * s + b2[idx];
  }
}

// ---------------- Kernel 1: h = SiLU(BN1(W1 @ x)), bf16 out -----------------
// Register-tiled fp32 GEMM: block tile M=128 x N=128, K-chunk 16 via LDS,
// thread tile 8x8. grid: (HW/128, B), block 256.
__global__ __launch_bounds__(256) void k1_cv1(
    const float* __restrict__ x, const float* __restrict__ W1,
    const float* __restrict__ g1, const float* __restrict__ b1,
    const float* __restrict__ m1, const float* __restrict__ v1,
    unsigned short* __restrict__ h) {
  __shared__ float ws[16][128];   // W1^T chunk: [kk][m]
  __shared__ float xs[16][128];   // x chunk:    [kk][n]
  const int b   = blockIdx.y;
  const int hw0 = blockIdx.x * 128;
  const int t   = threadIdx.x;
  const int tn  = t & 15;         // n-group
  const int tm  = t >> 4;         // m-group

  float acc[8][8];
#pragma unroll
  for (int i = 0; i < 8; ++i)
#pragma unroll
    for (int j = 0; j < 8; ++j) acc[i][j] = 0.f;

  const int m_l = t & 127;        // staging: lane-consecutive m / n
  for (int c0 = 0; c0 < C1_; c0 += 16) {
#pragma unroll
    for (int i = 0; i < 8; ++i) {
      int idx = t + i * 256;
      int kk = idx >> 7;          // thread reads 8 elems of one W1 row
      ws[kk][m_l] = W1[m_l * C1_ + c0 + kk];
    }
#pragma unroll
    for (int i = 0; i < 8; ++i) {
      int idx = t + i * 256;
      int kk = idx >> 7;
      xs[kk][m_l] = x[((size_t)b * C1_ + c0 + kk) * HW_ + hw0 + m_l];
    }
    __syncthreads();
#pragma unroll
    for (int kk = 0; kk < 16; ++kk) {
      float av[8], bv[8];
      *reinterpret_cast<float4*>(&av[0]) = *reinterpret_cast<const float4*>(&ws[kk][tm * 8]);
      *reinterpret_cast<float4*>(&av[4]) = *reinterpret_cast<const float4*>(&ws[kk][tm * 8 + 4]);
      *reinterpret_cast<float4*>(&bv[0]) = *reinterpret_cast<const float4*>(&xs[kk][tn * 8]);
      *reinterpret_cast<float4*>(&bv[4]) = *reinterpret_cast<const float4*>(&xs[kk][tn * 8 + 4]);
#pragma unroll
      for (int i = 0; i < 8; ++i)
#pragma unroll
        for (int j = 0; j < 8; ++j)
          acc[i][j] = fmaf(av[i], bv[j], acc[i][j]);
    }
    __syncthreads();
  }

  // epilogue: BN1 + SiLU, packed bf16 stores (16 B per row of 8)
#pragma unroll
  for (int i = 0; i < 8; ++i) {
    int o = tm * 8 + i;
    float s  = g1[o] * rsqrtf(v1[o] + EPS_);
    float sh = b1[o] - m1[o] * s;
    unsigned short pk[8];
#pragma unroll
    for (int j = 0; j < 8; ++j) {
      float val = fmaf(acc[i][j], s, sh);
      float sig = 1.f / (1.f + __expf(-val));
      pk[j] = f2bf(val * sig);
    }
    uint4* dst = reinterpret_cast<uint4*>(
        h + ((size_t)b * Cm_ + o) * HW_ + hw0 + tn * 8);
    *dst = *reinterpret_cast<const uint4*>(pk);
  }
}

// ---------------- Kernel 2a: softmax weights -> v_t[b][hw][cn] bf16 ---------
// grid: (W/8, H, B), block 256.
__global__ __launch_bounds__(256) void k2a_weights(
    const unsigned short* __restrict__ h,
    const float* __restrict__ Wg, const float* __restrict__ bg,
    const float* __restrict__ gg, const float* __restrict__ bgw,
    const float* __restrict__ mg, const float* __restrict__ vg,
    unsigned short* __restrict__ vt) {
  __shared__ unsigned short ht[Cm_ * 30];     // [c][r(3)][xx(10)] bf16
  __shared__ unsigned short vbuf[8][CN_];     // [px][c*9+n] bf16

  const int b  = blockIdx.z;
  const int y  = blockIdx.y;
  const int x0 = blockIdx.x * 8;
  const int t  = threadIdx.x;

  // phase 0: stage h halo tile (rows y-1..y+1, cols x0-1..x0+8), zero-padded
  for (int idx = t; idx < Cm_ * 30; idx += 256) {
    int c   = idx / 30;
    int rem = idx - c * 30;
    int r   = rem / 10;
    int xx  = rem - r * 10;
    int gy  = y + r - 1;
    int gx  = x0 + xx - 1;
    unsigned short val = 0;
    if (gy >= 0 && gy < H_ && gx >= 0 && gx < W_)
      val = h[((size_t)b * Cm_ + c) * HW_ + gy * W_ + gx];
    ht[idx] = val;
  }
  __syncthreads();

  // phase 1: per (c, px): 9->9 mixing + BN + softmax -> weighted patches
#pragma unroll
  for (int k = 0; k < 4; ++k) {
    int id = t + k * 256;       // 0..1023
    int c  = id >> 3;           // 0..127
    int px = id & 7;            // 0..7
    float p[9];
#pragma unroll
    for (int i = 0; i < 3; ++i)
#pragma unroll
      for (int j = 0; j < 3; ++j)
        p[i * 3 + j] = bf2f(ht[c * 30 + i * 10 + px + j]);
    float wv[9];
#pragma unroll
    for (int o = 0; o < 9; ++o) {
      float acc = bg[c * 9 + o];
#pragma unroll
      for (int i = 0; i < 9; ++i)
        acc = fmaf(Wg[c * 81 + o * 9 + i], p[i], acc);
      float s = gg[c * 9 + o] * rsqrtf(vg[c * 9 + o] + EPS_);
      wv[o] = (acc - mg[c * 9 + o]) * s + bgw[c * 9 + o];
    }
    float mx = wv[0];
#pragma unroll
    for (int o = 1; o < 9; ++o) mx = fmaxf(mx, wv[o]);
    float sum = 0.f;
#pragma unroll
    for (int o = 0; o < 9; ++o) { wv[o] = __expf(wv[o] - mx); sum += wv[o]; }
    float inv = 1.f / sum;
#pragma unroll
    for (int n = 0; n < 9; ++n)
      vbuf[px][c * 9 + n] = f2bf(p[n] * wv[n] * inv);
  }
  __syncthreads();

  // write-out: coalesced 16-B chunks, v_t[b][hw][cn]
  for (int idx = t; idx < 8 * (CN_ / 8); idx += 256) {   // 1152 chunks
    int px  = idx / 144;
    int off = idx - px * 144;
    const uint4* src = reinterpret_cast<const uint4*>(&vbuf[px][off * 8]);
    int hw = y * W_ + x0 + px;
    uint4* dst = reinterpret_cast<uint4*>(vt + ((size_t)b * HW_ + hw) * CN_ + off * 8);
    *dst = *src;
  }
}

// ---------------- Kernel 2b: out = x + relu(BN2(Wcb @ v_t + bc)) via MFMA ---
// grid: (HW/64, B), block 256 (4 waves). Wave w owns m-frags [4w..4w+3] x 4 n-frags.
__global__ __launch_bounds__(256) void k2b_gemm(
    const unsigned short* __restrict__ Wcb, const unsigned short* __restrict__ vt,
    const float* __restrict__ A2, const float* __restrict__ B2,
    const float* __restrict__ x, float* __restrict__ out) {
  const int b   = blockIdx.y;
  const int n0  = blockIdx.x * 64;
  const int t   = threadIdx.x;
  const int w   = __builtin_amdgcn_readfirstlane(t >> 6);
  const int l   = t & 63;
  const int l15 = l & 15;
  const int lhi = l >> 4;

  const unsigned short* aptr = Wcb + (size_t)(w * 64 + l15) * CN_ + 8 * lhi;
  const unsigned short* bptr = vt + ((size_t)b * HW_ + n0 + l15) * CN_ + 8 * lhi;

  f32x4 acc[4][4];
#pragma unroll
  for (int i = 0; i < 4; ++i)
#pragma unroll
    for (int nf = 0; nf < 4; ++nf) acc[i][nf] = (f32x4)0.f;

  bf16x8 a0[4], b0v[4], a1[4], b1v[4];

#define LOADA(DST, KK)                                                        \
  _Pragma("unroll") for (int i = 0; i < 4; ++i)                               \
      DST[i] = *reinterpret_cast<const bf16x8*>(aptr + i * 16 * CN_ + (KK));
#define LOADB(DST, KK)                                                        \
  _Pragma("unroll") for (int nf = 0; nf < 4; ++nf)                            \
      DST[nf] = *reinterpret_cast<const bf16x8*>(bptr + nf * 16 * CN_ + (KK));
#define MF(AS, BS)                                                            \
  _Pragma("unroll") for (int i = 0; i < 4; ++i)                               \
      _Pragma("unroll") for (int nf = 0; nf < 4; ++nf)                        \
          acc[i][nf] = __builtin_amdgcn_mfma_f32_16x16x32_bf16(               \
              AS[i], BS[nf], acc[i][nf], 0, 0, 0);

  LOADA(a0, 0) LOADB(b0v, 0)
  for (int kb = 0; kb < 17; ++kb) {
    const int kk = kb * 64;
    LOADA(a1, kk + 32) LOADB(b1v, kk + 32)
    MF(a0, b0v)
    LOADA(a0, kk + 64) LOADB(b0v, kk + 64)
    MF(a1, b1v)
  }
  LOADA(a1, 1120) LOADB(b1v, 1120)
  MF(a0, b0v)   // kk = 1088
  MF(a1, b1v)   // kk = 1120

  // epilogue: BN2 + ReLU + residual
#pragma unroll
  for (int i = 0; i < 4; ++i) {
#pragma unroll
    for (int r = 0; r < 4; ++r) {
      int o = w * 64 + i * 16 + lhi * 4 + r;
      float sA = A2[o], sB = B2[o];
#pragma unroll
      for (int nf = 0; nf < 4; ++nf) {
        float val = fmaf(acc[i][nf][r], sA, sB);
        val = fmaxf(val, 0.f);
        size_t idx = ((size_t)b * C2_ + o) * HW_ + n0 + nf * 16 + l15;
        out[idx] = x[idx] + val;
      }
    }
  }
#undef LOADA
#undef LOADB
#undef MF
}

extern "C" void kernel_launch(void* const* d_in, const int* in_sizes, int n_in,
                              void* d_out, int out_size, void* d_ws, size_t ws_size,
                              hipStream_t stream) {
  (void)in_sizes; (void)n_in; (void)out_size; (void)ws_size;
  const float* x   = (const float*)d_in[0];
  const float* W1  = (const float*)d_in[1];
  const float* g1  = (const float*)d_in[2];
  const float* b1  = (const float*)d_in[3];
  const float* m1  = (const float*)d_in[4];
  const float* v1  = (const float*)d_in[5];
  const float* Wg  = (const float*)d_in[6];
  const float* bg  = (const float*)d_in[7];
  const float* gg  = (const float*)d_in[8];
  const float* bgw = (const float*)d_in[9];
  const float* mg  = (const float*)d_in[10];
  const float* vg  = (const float*)d_in[11];
  const float* Wc  = (const float*)d_in[12];
  const float* bc  = (const float*)d_in[13];
  const float* g2  = (const float*)d_in[14];
  const float* b2  = (const float*)d_in[15];
  const float* m2  = (const float*)d_in[16];
  const float* v2  = (const float*)d_in[17];
  float* outp = (float*)d_out;

  // workspace layout (bytes):
  //   h   : bf16 [8][128][6400]      13,107,200
  //   v_t : bf16 [8][6400][1152]    117,964,800
  //   Wcb : bf16 [256][1152]            589,824
  //   A2,B2: f32 [256] each               2,048
  char* ws = (char*)d_ws;
  unsigned short* h   = (unsigned short*)ws;
  unsigned short* vt  = (unsigned short*)(ws + 13107200);
  unsigned short* Wcb = (unsigned short*)(ws + 13107200 + 117964800);
  float*          A2  = (float*)(ws + 13107200 + 117964800 + 589824);
  float*          B2  = A2 + C2_;

  k0_prep<<<dim3((C2_ * CN_ + 255) / 256), 256, 0, stream>>>(
      Wc, bc, g2, b2, m2, v2, Wcb, A2, B2);

  dim3 grid1(HW_ / 128, B_);
  k1_cv1<<<grid1, 256, 0, stream>>>(x, W1, g1, b1, m1, v1, h);

  dim3 grid2a(W_ / 8, H_, B_);
  k2a_weights<<<grid2a, 256, 0, stream>>>(h, Wg, bg, gg, bgw, mg, vg, vt);

  dim3 grid2b(HW_ / 64, B_);
  k2b_gemm<<<grid2b, 256, 0, stream>>>(Wcb, vt, A2, B2, x, outp);
}